// Round 6
// baseline (417.934 us; speedup 1.0000x reference)
//
#include <hip/hip_runtime.h>

#define N_NODES 50000
#define N_EDGES 800000
#define IN_DIM 512
#define NEG_SLOPE 0.2f

typedef short short8 __attribute__((ext_vector_type(8)));
typedef float f32x16 __attribute__((ext_vector_type(16)));
typedef __attribute__((address_space(3))) unsigned int lds_u32;
typedef const __attribute__((address_space(1))) unsigned int glb_u32;

// ---------------- bf16 helpers ----------------
__device__ __forceinline__ unsigned bf16rne(float f) {
  union { float f; unsigned u; } v;
  v.f = f;
  return (v.u + 0x7FFFu + ((v.u >> 16) & 1u)) >> 16;
}
// truncation split of A: hi = trunc16(f); lo = trunc16(f - hi). err ~2^-16.
__device__ __forceinline__ void tsplit8(float4 a, float4 b, short8& hi,
                                        short8& lo) {
  float fa[8] = {a.x, a.y, a.z, a.w, b.x, b.y, b.z, b.w};
#pragma unroll
  for (int i = 0; i < 8; i++) {
    unsigned u = __float_as_uint(fa[i]);
    hi[i] = (short)(u >> 16);
    float lof = fa[i] - __uint_as_float(u & 0xffff0000u);
    lo[i] = (short)(__float_as_uint(lof) >> 16);
  }
}

// ---------------- W pre-pack (hi plane only) into MFMA B-frag order --------
__global__ void pack_w(const float* __restrict__ W, short* __restrict__ Bhi,
                       int N) {
  int k = blockIdx.x, n = threadIdx.x;
  float w = W[(size_t)k * N + n];
  int ksub = k >> 4, kh = (k >> 3) & 1, j = k & 7;
  int nsub = n >> 5, lane2 = (n & 31) | (kh << 5);
  size_t off = (((size_t)ksub * (N >> 5) + nsub) * 64 + lane2) * 8 + j;
  Bhi[off] = (short)bf16rne(w);
}

// ---------------- split-bf16 MFMA GEMM v8 ----------------
// Generalized v7 (T4 counted-vmcnt double-buffer, A+B via global_load_lds):
//  NTILES = col-split among the 4 waves. Layer 1: NTILES=2 -> 64-row blocks,
//  128 cols/wave, 16 MFMA/wave/step (2x v7 compute density, half the B L2
//  re-streaming). Layer 2: NTILES=1 -> 128-row blocks (v7 shape).
// Epilogue emits exp-tables for the separable attention coefficient:
//  elt = {exp(el), exp(0.2 el)}, ert = {exp(er), exp(0.2 er)} per (row,head);
//  consumer uses  a = (E1*F1 > 1) ? E1*F1 : E2*F2  ==  exp(leaky(el+er)).
template <int K, int NSUBS, int NTILES>
__global__ __launch_bounds__(256) void gemm_mfma(
    const float* __restrict__ A, const short* __restrict__ Bhi_,
    unsigned short* __restrict__ Cb, const float* __restrict__ alv,
    const float* __restrict__ arv, float2* __restrict__ elt,
    float2* __restrict__ ert, int M) {
  constexpr int N = NSUBS * 32;
  constexpr int MTILES = 4 / NTILES;     // row-tiles of 32 per block
  constexpr int BROWS = MTILES * 32;     // rows per block
  constexpr int T = K / 32;              // K-steps of 32 floats
  constexpr int MT = MTILES;             // A gloads per wave per step
  constexpr int GB = NSUBS / 2;          // B gloads per wave per step
  constexpr int NSUBT = NSUBS / NTILES;  // 32-col subtiles per wave
  constexpr int HPW = NSUBT / 2;         // heads (64 cols) per wave
  constexpr int NHEADS = NSUBS / 2;      // total heads
  constexpr int BSTEP_S = NSUBS * 1024;  // shorts per B K-step
  static_assert(MT + GB == 5 || MT + GB == 6, "vmcnt literal coverage");
  __shared__ float ldsA[2][BROWS * 32];  // [buf][row*32 + pos*4 + e]
  __shared__ short ldsB[2][BSTEP_S];     // [buf][frag-linear]

  const int tid = threadIdx.x;
  const int lane = tid & 63;
  const int w = tid >> 6;
  const int l31 = lane & 31;
  const int half = lane >> 5;
  const int local_mt = w / NTILES;
  const int ntile = w % NTILES;
  const int block_row0 = blockIdx.x * BROWS;

  // --- A staging source pointers (per-lane, carry the inverse swizzle) ---
  // gload (w,q) covers seg = w*MT+q (8 rows x 128B). Lane i -> row
  // r = seg*8 + (i>>3), pos p = i&7; pos p holds logical chunk c = p^(r&7).
  const float* gsrcA[MT];
#pragma unroll
  for (int q = 0; q < MT; q++) {
    int seg = w * MT + q;
    int r = seg * 8 + (lane >> 3);
    int c = (lane & 7) ^ (r & 7);
    int grow = block_row0 + r;
    if (grow > M - 1) grow = M - 1;  // clamp tail rows (dup rows harmless)
    gsrcA[q] = A + (size_t)grow * K + c * 4;
  }
  // B staging source (linear copy of the packed-B K-step region)
  const short* bsrc = Bhi_ + lane * 8;

  // row this lane reads back from LDS-A, and its swizzle key
  const int arow = local_mt * 32 + l31;
  const int rs = arow & 7;

  f32x16 acc[NSUBT] = {};

  auto STAGE = [&](int b, int t) {
#pragma unroll
    for (int q = 0; q < MT; q++) {
      __builtin_amdgcn_global_load_lds((glb_u32*)(gsrcA[q] + t * 32),
                                       (lds_u32*)&ldsA[b][(w * MT + q) * 256],
                                       16, 0, 0);
    }
#pragma unroll
    for (int j = 0; j < GB; j++) {
      __builtin_amdgcn_global_load_lds(
          (glb_u32*)(bsrc + (size_t)t * BSTEP_S + (w * GB + j) * 512),
          (lds_u32*)&ldsB[b][(w * GB + j) * 512], 16, 0, 0);
    }
  };

  // --- prologue: stage K-step 0 ---
  STAGE(0, 0);

  int buf = 0;
  for (int t = 0; t < T; t++) {
    if (t + 1 < T) {
      STAGE(buf ^ 1, t + 1);  // issue next step; stays in flight across barrier
      if constexpr (MT + GB == 5)
        asm volatile("s_waitcnt vmcnt(5)" ::: "memory");
      else
        asm volatile("s_waitcnt vmcnt(6)" ::: "memory");
    } else {
      asm volatile("s_waitcnt vmcnt(0)" ::: "memory");
    }
    __builtin_amdgcn_s_barrier();  // all waves' step-t stages landed

    const float* lA = ldsA[buf];
    const short* lB = ldsB[buf];
#pragma unroll
    for (int u = 0; u < 2; u++) {
      int c0 = u * 4 + half * 2;
      float4 a0 = *(const float4*)&lA[arow * 32 + (c0 ^ rs) * 4];
      float4 a1 = *(const float4*)&lA[arow * 32 + ((c0 + 1) ^ rs) * 4];
      short8 ah, al8;
      tsplit8(a0, a1, ah, al8);
#pragma unroll
      for (int j = 0; j < NSUBT; j++) {
        short8 cbj = *(const short8*)&lB[(u * NSUBS + ntile * NSUBT + j) * 512 +
                                         lane * 8];
        acc[j] = __builtin_amdgcn_mfma_f32_32x32x16_bf16(ah, cbj, acc[j], 0, 0, 0);
        acc[j] =
            __builtin_amdgcn_mfma_f32_32x32x16_bf16(al8, cbj, acc[j], 0, 0, 0);
      }
    }
    // WAR guard: my LDS reads retired, then all waves synced, before next
    // iter re-stages this buffer.
    asm volatile("s_waitcnt lgkmcnt(0)" ::: "memory");
    __builtin_amdgcn_s_barrier();
    buf ^= 1;
  }

  // C/D layout (m74/m101): col=lane&31, row=(r&3)+8*(r>>2)+4*half
  const int mrow0 = block_row0 + local_mt * 32;
#pragma unroll
  for (int h = 0; h < HPW; h++) {
    int c0 = ntile * NSUBT * 32 + 2 * h * 32 + l31;
    float wa0 = alv[c0], wa1 = alv[c0 + 32];
    float wr0 = arv[c0], wr1 = arv[c0 + 32];
#pragma unroll
    for (int r = 0; r < 16; r++) {
      int roff = (r & 3) + 8 * (r >> 2) + 4 * half;
      int row = mrow0 + roff;
      float v0 = acc[2 * h][r], v1 = acc[2 * h + 1][r];
      if (row < M) {
        Cb[(size_t)row * N + c0] = (unsigned short)bf16rne(v0);
        Cb[(size_t)row * N + c0 + 32] = (unsigned short)bf16rne(v1);
      }
      float elv = v0 * wa0 + v1 * wa1;
      float erv = v0 * wr0 + v1 * wr1;
#pragma unroll
      for (int off = 1; off < 32; off <<= 1) {
        elv += __shfl_xor(elv, off);
        erv += __shfl_xor(erv, off);
      }
      if (l31 == 0 && row < M) {
        int hg = ntile * HPW + h;
        elt[(size_t)row * NHEADS + hg] =
            make_float2(__expf(elv), __expf(NEG_SLOPE * elv));
        ert[(size_t)row * NHEADS + hg] =
            make_float2(__expf(erv), __expf(NEG_SLOPE * erv));
      }
    }
  }
}

// ---------------- CSR build ----------------
__global__ void hist_kernel(const int* __restrict__ dst,
                            int* __restrict__ counts) {
  int e = blockIdx.x * blockDim.x + threadIdx.x;
  if (e < N_EDGES) atomicAdd(&counts[dst[e]], 1);
}

#define NSCAN 196  // ceil(50000/256)
__global__ __launch_bounds__(256) void scan_part(const int* __restrict__ counts,
                                                 int* __restrict__ offsets,
                                                 int* __restrict__ bsums) {
  __shared__ int sh[256];
  int t = threadIdx.x;
  int i = blockIdx.x * 256 + t;
  int v = (i < N_NODES) ? counts[i] : 0;
  sh[t] = v;
  __syncthreads();
  for (int o = 1; o < 256; o <<= 1) {
    int x = (t >= o) ? sh[t - o] : 0;
    __syncthreads();
    sh[t] += x;
    __syncthreads();
  }
  if (i < N_NODES) offsets[i] = sh[t] - v;
  if (t == 255) bsums[blockIdx.x] = sh[255];
}
__global__ __launch_bounds__(256) void scan_top(int* __restrict__ bsums) {
  __shared__ int sh[256];
  int t = threadIdx.x;
  int v = (t < NSCAN) ? bsums[t] : 0;
  sh[t] = v;
  __syncthreads();
  for (int o = 1; o < 256; o <<= 1) {
    int x = (t >= o) ? sh[t - o] : 0;
    __syncthreads();
    sh[t] += x;
    __syncthreads();
  }
  if (t < NSCAN) bsums[t] = sh[t] - v;
}
__global__ __launch_bounds__(256) void scan_add(int* __restrict__ offsets,
                                                const int* __restrict__ bsums) {
  int i = blockIdx.x * 256 + threadIdx.x;
  if (i < N_NODES) offsets[i] += bsums[blockIdx.x];
  if (i == 0) offsets[N_NODES] = N_EDGES;
}

__global__ void scatter_kernel(const int* __restrict__ src,
                               const int* __restrict__ dst,
                               const int* __restrict__ offsets,
                               int* __restrict__ fill,
                               int* __restrict__ csr_src) {
  int e = blockIdx.x * blockDim.x + threadIdx.x;
  if (e < N_EDGES) {
    int d = dst[e];
    int pos = offsets[d] + atomicAdd(&fill[d], 1);
    csr_src[pos] = src[e];
  }
}

// ---------------- aggregation layer 1 v3 ----------------
// Coefficient via exp-tables (no transcendental in edge loop):
//   a = (E1_s*F1_n > 1) ? E1_s*F1_n : E2_s*F2_n  == exp(leaky(el_s+er_n)).
// uint4 gathers (16B/lane, 32 lanes/row, 2 edges/wave in parallel), 2x edge
// unroll, fused softmax denominator.
__global__ __launch_bounds__(256) void agg1_kernel(
    const int* __restrict__ offsets, const int* __restrict__ csr_src,
    const float2* __restrict__ elt, const float2* __restrict__ ert,
    const unsigned short* __restrict__ fb, const float* __restrict__ bias,
    float* __restrict__ h1) {
  __shared__ float red[3][256];
  __shared__ float dred[3][32];
  int n = blockIdx.x;
  int t = threadIdx.x;
  int w = t >> 6, lane = t & 63;
  int l31 = lane & 31;
  int eslot = lane >> 5;      // 0/1: which edge of the pair this half-wave does
  int h = l31 >> 3;           // head for this lane's 8 dims
  int slot = w * 2 + eslot;   // 0..7 edge slots per node
  int off0 = offsets[n], deg = offsets[n + 1] - off0;
  float2 fv = ert[n * 4 + h];  // {F1, F2}
  float4 aLo = {0.f, 0.f, 0.f, 0.f}, aHi = {0.f, 0.f, 0.f, 0.f};
  float4 bLo = {0.f, 0.f, 0.f, 0.f}, bHi = {0.f, 0.f, 0.f, 0.f};
  float sden = 0.f;
  int i = slot;
  for (; i + 8 < deg; i += 16) {
    int s0 = csr_src[off0 + i];
    int s1 = csr_src[off0 + i + 8];
    uint4 p0 = *(const uint4*)(fb + (size_t)s0 * 256 + l31 * 8);
    uint4 p1 = *(const uint4*)(fb + (size_t)s1 * 256 + l31 * 8);
    float2 q0 = elt[s0 * 4 + h];
    float2 q1 = elt[s1 * 4 + h];
    float t10 = q0.x * fv.x, t20 = q0.y * fv.y;
    float t11 = q1.x * fv.x, t21 = q1.y * fv.y;
    float a0 = t10 > 1.f ? t10 : t20;
    float a1 = t11 > 1.f ? t11 : t21;
    sden += a0 + a1;
    aLo.x += a0 * __uint_as_float(p0.x << 16);
    aLo.y += a0 * __uint_as_float(p0.x & 0xffff0000u);
    aLo.z += a0 * __uint_as_float(p0.y << 16);
    aLo.w += a0 * __uint_as_float(p0.y & 0xffff0000u);
    aHi.x += a0 * __uint_as_float(p0.z << 16);
    aHi.y += a0 * __uint_as_float(p0.z & 0xffff0000u);
    aHi.z += a0 * __uint_as_float(p0.w << 16);
    aHi.w += a0 * __uint_as_float(p0.w & 0xffff0000u);
    bLo.x += a1 * __uint_as_float(p1.x << 16);
    bLo.y += a1 * __uint_as_float(p1.x & 0xffff0000u);
    bLo.z += a1 * __uint_as_float(p1.y << 16);
    bLo.w += a1 * __uint_as_float(p1.y & 0xffff0000u);
    bHi.x += a1 * __uint_as_float(p1.z << 16);
    bHi.y += a1 * __uint_as_float(p1.z & 0xffff0000u);
    bHi.z += a1 * __uint_as_float(p1.w << 16);
    bHi.w += a1 * __uint_as_float(p1.w & 0xffff0000u);
  }
  if (i < deg) {
    int s0 = csr_src[off0 + i];
    uint4 p0 = *(const uint4*)(fb + (size_t)s0 * 256 + l31 * 8);
    float2 q0 = elt[s0 * 4 + h];
    float t10 = q0.x * fv.x, t20 = q0.y * fv.y;
    float a0 = t10 > 1.f ? t10 : t20;
    sden += a0;
    aLo.x += a0 * __uint_as_float(p0.x << 16);
    aLo.y += a0 * __uint_as_float(p0.x & 0xffff0000u);
    aLo.z += a0 * __uint_as_float(p0.y << 16);
    aLo.w += a0 * __uint_as_float(p0.y & 0xffff0000u);
    aHi.x += a0 * __uint_as_float(p0.z << 16);
    aHi.y += a0 * __uint_as_float(p0.z & 0xffff0000u);
    aHi.z += a0 * __uint_as_float(p0.w << 16);
    aHi.w += a0 * __uint_as_float(p0.w & 0xffff0000u);
  }
  // combine the 2-edge unroll
  aLo.x += bLo.x; aLo.y += bLo.y; aLo.z += bLo.z; aLo.w += bLo.w;
  aHi.x += bHi.x; aHi.y += bHi.y; aHi.z += bHi.z; aHi.w += bHi.w;
  // combine eslots (lane ^ 32)
  aLo.x += __shfl_xor(aLo.x, 32);
  aLo.y += __shfl_xor(aLo.y, 32);
  aLo.z += __shfl_xor(aLo.z, 32);
  aLo.w += __shfl_xor(aLo.w, 32);
  aHi.x += __shfl_xor(aHi.x, 32);
  aHi.y += __shfl_xor(aHi.y, 32);
  aHi.z += __shfl_xor(aHi.z, 32);
  aHi.w += __shfl_xor(aHi.w, 32);
  sden += __shfl_xor(sden, 32);
  if (w && lane < 32) {
    *(float4*)(&red[w - 1][l31 * 8]) = aLo;
    *(float4*)(&red[w - 1][l31 * 8 + 4]) = aHi;
    dred[w - 1][l31] = sden;
  }
  __syncthreads();
  if (w == 0 && lane < 32) {
    float den = sden;
#pragma unroll
    for (int j = 0; j < 3; j++) {
      float4 rL = *(float4*)(&red[j][l31 * 8]);
      float4 rH = *(float4*)(&red[j][l31 * 8 + 4]);
      aLo.x += rL.x; aLo.y += rL.y; aLo.z += rL.z; aLo.w += rL.w;
      aHi.x += rH.x; aHi.y += rH.y; aHi.z += rH.z; aHi.w += rH.w;
      den += dred[j][l31];
    }
    float invd = den > 0.f ? 1.0f / den : 0.f;
    float4 b0 = ((const float4*)bias)[l31 * 2];
    float4 b1 = ((const float4*)bias)[l31 * 2 + 1];
    float o[8] = {aLo.x * invd + b0.x, aLo.y * invd + b0.y,
                  aLo.z * invd + b0.z, aLo.w * invd + b0.w,
                  aHi.x * invd + b1.x, aHi.y * invd + b1.y,
                  aHi.z * invd + b1.z, aHi.w * invd + b1.w};
#pragma unroll
    for (int j = 0; j < 8; j++) o[j] = o[j] > 0.f ? o[j] : __expf(o[j]) - 1.0f;
    float4 o0 = {o[0], o[1], o[2], o[3]};
    float4 o1 = {o[4], o[5], o[6], o[7]};
    *(float4*)(h1 + (size_t)n * 256 + l31 * 8) = o0;
    *(float4*)(h1 + (size_t)n * 256 + l31 * 8 + 4) = o1;
  }
}

// ---------------- aggregation layer 2 v3 (tables, fused den, 2x unroll) -----
__global__ __launch_bounds__(256) void agg2_kernel(
    const int* __restrict__ offsets, const int* __restrict__ csr_src,
    const float2* __restrict__ elt, const float2* __restrict__ ert,
    const unsigned short* __restrict__ fb2, const float* __restrict__ bias,
    float* __restrict__ out) {
  int w = threadIdx.x >> 6, lane = threadIdx.x & 63;
  int n = blockIdx.x * 4 + w;
  if (n >= N_NODES) return;
  int dg = lane & 15, eslot = lane >> 4;
  int off0 = offsets[n], deg = offsets[n + 1] - off0;
  float2 fv = ert[n];
  float4 acc = {0.f, 0.f, 0.f, 0.f};
  float4 acc2 = {0.f, 0.f, 0.f, 0.f};
  float sden = 0.f;
  int i = eslot;
  for (; i + 4 < deg; i += 8) {
    int s0 = csr_src[off0 + i];
    int s1 = csr_src[off0 + i + 4];
    uint2 p0 = *(const uint2*)(fb2 + (size_t)s0 * 64 + dg * 4);
    uint2 p1 = *(const uint2*)(fb2 + (size_t)s1 * 64 + dg * 4);
    float2 q0 = elt[s0];
    float2 q1 = elt[s1];
    float t10 = q0.x * fv.x, t20 = q0.y * fv.y;
    float t11 = q1.x * fv.x, t21 = q1.y * fv.y;
    float a0 = t10 > 1.f ? t10 : t20;
    float a1 = t11 > 1.f ? t11 : t21;
    sden += a0 + a1;
    acc.x += a0 * __uint_as_float(p0.x << 16);
    acc.y += a0 * __uint_as_float(p0.x & 0xffff0000u);
    acc.z += a0 * __uint_as_float(p0.y << 16);
    acc.w += a0 * __uint_as_float(p0.y & 0xffff0000u);
    acc2.x += a1 * __uint_as_float(p1.x << 16);
    acc2.y += a1 * __uint_as_float(p1.x & 0xffff0000u);
    acc2.z += a1 * __uint_as_float(p1.y << 16);
    acc2.w += a1 * __uint_as_float(p1.y & 0xffff0000u);
  }
  if (i < deg) {
    int s0 = csr_src[off0 + i];
    uint2 p0 = *(const uint2*)(fb2 + (size_t)s0 * 64 + dg * 4);
    float2 q0 = elt[s0];
    float t10 = q0.x * fv.x, t20 = q0.y * fv.y;
    float a0 = t10 > 1.f ? t10 : t20;
    sden += a0;
    acc.x += a0 * __uint_as_float(p0.x << 16);
    acc.y += a0 * __uint_as_float(p0.x & 0xffff0000u);
    acc.z += a0 * __uint_as_float(p0.y << 16);
    acc.w += a0 * __uint_as_float(p0.y & 0xffff0000u);
  }
  acc.x += acc2.x;
  acc.y += acc2.y;
  acc.z += acc2.z;
  acc.w += acc2.w;
#pragma unroll
  for (int off = 16; off < 64; off <<= 1) {
    acc.x += __shfl_xor(acc.x, off);
    acc.y += __shfl_xor(acc.y, off);
    acc.z += __shfl_xor(acc.z, off);
    acc.w += __shfl_xor(acc.w, off);
    sden += __shfl_xor(sden, off);
  }
  if (eslot == 0) {
    float invd = sden > 0.f ? 1.0f / sden : 0.f;
    float4 b = ((const float4*)bias)[dg];
    float4 ov = {acc.x * invd + b.x, acc.y * invd + b.y, acc.z * invd + b.z,
                 acc.w * invd + b.w};
    *(float4*)(out + (size_t)n * 64 + dg * 4) = ov;
  }
}

extern "C" void kernel_launch(void* const* d_in, const int* in_sizes, int n_in,
                              void* d_out, int out_size, void* d_ws,
                              size_t ws_size, hipStream_t stream) {
  const float* features = (const float*)d_in[0];
  const float* W1 = (const float*)d_in[1];
  const float* al1 = (const float*)d_in[2];
  const float* ar1 = (const float*)d_in[3];
  const float* b1 = (const float*)d_in[4];
  const float* W2 = (const float*)d_in[5];
  const float* al2 = (const float*)d_in[6];
  const float* ar2 = (const float*)d_in[7];
  const float* b2 = (const float*)d_in[8];
  const int* src = (const int*)d_in[9];
  const int* dst = (const int*)d_in[10];
  float* out = (float*)d_out;

  // Workspace (~84 MB):
  //  h1 fp32 [N,256] (agg1 out -> gemm2 A)
  //  fb bf16 [N,256] (gemm1 out) -> dead after agg1 -> fb2 bf16 [N,64] reuses
  //  exp-tables: elt/ert float2 per (node,head)
  float* h1 = (float*)d_ws;                                            // 51.2
  unsigned short* fb = (unsigned short*)(h1 + (size_t)N_NODES * 256);  // 25.6
  unsigned short* fb2 = fb;  // reuse (6.4 MB needed)
  float2* elt1 = (float2*)(fb + (size_t)N_NODES * 256);
  float2* ert1 = elt1 + (size_t)N_NODES * 4;
  float2* elt2 = ert1 + (size_t)N_NODES * 4;
  float2* ert2 = elt2 + N_NODES;
  int* counts = (int*)(ert2 + N_NODES);
  int* offsets = counts + N_NODES;
  int* fill = offsets + N_NODES + 1;
  int* csr_src = fill + N_NODES;
  int* bsums = csr_src + N_EDGES;

  // W packs (hi plane only): b1 in d_out (dead until agg2);
  // b2 in `fill` (dead after scatter).
  short* b1hi = (short*)d_out;   // 512*256 shorts = 262 KB << 12.8 MB
  short* b2hi = (short*)fill;    // 256*64 shorts = 32 KB << 200 KB

  // --- CSR build ---
  hipMemsetAsync(counts, 0, N_NODES * sizeof(int), stream);
  hipMemsetAsync(fill, 0, N_NODES * sizeof(int), stream);
  hist_kernel<<<(N_EDGES + 255) / 256, 256, 0, stream>>>(dst, counts);
  scan_part<<<NSCAN, 256, 0, stream>>>(counts, offsets, bsums);
  scan_top<<<1, 256, 0, stream>>>(bsums);
  scan_add<<<NSCAN, 256, 0, stream>>>(offsets, bsums);
  scatter_kernel<<<(N_EDGES + 255) / 256, 256, 0, stream>>>(src, dst, offsets,
                                                            fill, csr_src);

  // --- weight packing ---
  pack_w<<<512, 256, 0, stream>>>(W1, b1hi, 256);
  pack_w<<<256, 64, 0, stream>>>(W2, b2hi, 64);

  // --- layer 1 (el/er exp-tables fused into gemm epilogue) ---
  gemm_mfma<IN_DIM, 8, 2><<<782, 256, 0, stream>>>(features, b1hi, fb, al1,
                                                   ar1, elt1, ert1, N_NODES);
  agg1_kernel<<<N_NODES, 256, 0, stream>>>(offsets, csr_src, elt1, ert1, fb,
                                           b1, h1);

  // --- layer 2 ---
  gemm_mfma<256, 2, 1><<<391, 256, 0, stream>>>(h1, b2hi, fb2, al2, ar2, elt2,
                                                ert2, N_NODES);
  agg2_kernel<<<(N_NODES + 3) / 4, 256, 0, stream>>>(offsets, csr_src, elt2,
                                                     ert2, fb2, b2, out);
}

// Round 7
// 408.523 us; speedup vs baseline: 1.0230x; 1.0230x over previous
//
#include <hip/hip_runtime.h>

#define N_NODES 50000
#define N_EDGES 800000
#define IN_DIM 512
#define NEG_SLOPE 0.2f

typedef short short8 __attribute__((ext_vector_type(8)));
typedef float f32x16 __attribute__((ext_vector_type(16)));
typedef __attribute__((address_space(3))) unsigned int lds_u32;
typedef const __attribute__((address_space(1))) unsigned int glb_u32;

// ---------------- bf16 helpers ----------------
__device__ __forceinline__ unsigned bf16rne(float f) {
  union { float f; unsigned u; } v;
  v.f = f;
  return (v.u + 0x7FFFu + ((v.u >> 16) & 1u)) >> 16;
}
// truncation split of A: hi = trunc16(f); lo = trunc16(f - hi). err ~2^-16.
__device__ __forceinline__ void tsplit8(float4 a, float4 b, short8& hi,
                                        short8& lo) {
  float fa[8] = {a.x, a.y, a.z, a.w, b.x, b.y, b.z, b.w};
#pragma unroll
  for (int i = 0; i < 8; i++) {
    unsigned u = __float_as_uint(fa[i]);
    hi[i] = (short)(u >> 16);
    float lof = fa[i] - __uint_as_float(u & 0xffff0000u);
    lo[i] = (short)(__float_as_uint(lof) >> 16);
  }
}

// ---------------- W pre-pack (hi plane only) into MFMA B-frag order --------
__global__ void pack_w(const float* __restrict__ W, short* __restrict__ Bhi,
                       int N) {
  int k = blockIdx.x, n = threadIdx.x;
  float w = W[(size_t)k * N + n];
  int ksub = k >> 4, kh = (k >> 3) & 1, j = k & 7;
  int nsub = n >> 5, lane2 = (n & 31) | (kh << 5);
  size_t off = (((size_t)ksub * (N >> 5) + nsub) * 64 + lane2) * 8 + j;
  Bhi[off] = (short)bf16rne(w);
}

// ---------------- split-bf16 MFMA GEMM v9 ----------------
// v7 geometry (empirically best: NTILES=4 -> 32-row blocks, 5 loads/wave/step,
// counted vmcnt(5), grid 1563) + exp-table epilogue. T4 counted-vmcnt
// double-buffer, A+B staged via global_load_lds, XOR bank swizzle on A's
// global source (rule #21). Layer 2: NTILES=1 (128-row blocks).
// Epilogue emits exp-tables for the separable attention coefficient:
//  elt = {exp(el), exp(0.2 el)}, ert = {exp(er), exp(0.2 er)} per (row,head);
//  consumer uses  a = (E1*F1 > 1) ? E1*F1 : E2*F2  ==  exp(leaky(el+er)).
template <int K, int NSUBS, int NTILES>
__global__ __launch_bounds__(256) void gemm_mfma(
    const float* __restrict__ A, const short* __restrict__ Bhi_,
    unsigned short* __restrict__ Cb, const float* __restrict__ alv,
    const float* __restrict__ arv, float2* __restrict__ elt,
    float2* __restrict__ ert, int M) {
  constexpr int N = NSUBS * 32;
  constexpr int MTILES = 4 / NTILES;     // row-tiles of 32 per block
  constexpr int BROWS = MTILES * 32;     // rows per block
  constexpr int T = K / 32;              // K-steps of 32 floats
  constexpr int MT = MTILES;             // A gloads per wave per step
  constexpr int GB = NSUBS / 2;          // B gloads per wave per step
  constexpr int NSUBT = NSUBS / NTILES;  // 32-col subtiles per wave
  constexpr int HPW = NSUBT / 2;         // heads (64 cols) per wave
  constexpr int NHEADS = NSUBS / 2;      // total heads
  constexpr int BSTEP_S = NSUBS * 1024;  // shorts per B K-step
  static_assert(MT + GB == 5, "vmcnt literal assumes 5 loads/wave/step");
  __shared__ float ldsA[2][BROWS * 32];  // [buf][row*32 + pos*4 + e]
  __shared__ short ldsB[2][BSTEP_S];     // [buf][frag-linear]

  const int tid = threadIdx.x;
  const int lane = tid & 63;
  const int w = tid >> 6;
  const int l31 = lane & 31;
  const int half = lane >> 5;
  const int local_mt = w / NTILES;
  const int ntile = w % NTILES;
  const int block_row0 = blockIdx.x * BROWS;

  // --- A staging source pointers (per-lane, carry the inverse swizzle) ---
  // gload (w,q) covers seg = w*MT+q (8 rows x 128B). Lane i -> row
  // r = seg*8 + (i>>3), pos p = i&7; pos p holds logical chunk c = p^(r&7).
  const float* gsrcA[MT];
#pragma unroll
  for (int q = 0; q < MT; q++) {
    int seg = w * MT + q;
    int r = seg * 8 + (lane >> 3);
    int c = (lane & 7) ^ (r & 7);
    int grow = block_row0 + r;
    if (grow > M - 1) grow = M - 1;  // clamp tail rows (dup rows harmless)
    gsrcA[q] = A + (size_t)grow * K + c * 4;
  }
  // B staging source (linear copy of the packed-B K-step region)
  const short* bsrc = Bhi_ + lane * 8;

  // row this lane reads back from LDS-A, and its swizzle key
  const int arow = local_mt * 32 + l31;
  const int rs = arow & 7;

  f32x16 acc[NSUBT] = {};

  auto STAGE = [&](int b, int t) {
#pragma unroll
    for (int q = 0; q < MT; q++) {
      __builtin_amdgcn_global_load_lds((glb_u32*)(gsrcA[q] + t * 32),
                                       (lds_u32*)&ldsA[b][(w * MT + q) * 256],
                                       16, 0, 0);
    }
#pragma unroll
    for (int j = 0; j < GB; j++) {
      __builtin_amdgcn_global_load_lds(
          (glb_u32*)(bsrc + (size_t)t * BSTEP_S + (w * GB + j) * 512),
          (lds_u32*)&ldsB[b][(w * GB + j) * 512], 16, 0, 0);
    }
  };

  // --- prologue: stage K-step 0 ---
  STAGE(0, 0);

  int buf = 0;
  for (int t = 0; t < T; t++) {
    if (t + 1 < T) {
      STAGE(buf ^ 1, t + 1);  // issue next step; stays in flight across barrier
      asm volatile("s_waitcnt vmcnt(5)" ::: "memory");  // step-t loads done
    } else {
      asm volatile("s_waitcnt vmcnt(0)" ::: "memory");
    }
    __builtin_amdgcn_s_barrier();  // all waves' step-t stages landed

    const float* lA = ldsA[buf];
    const short* lB = ldsB[buf];
#pragma unroll
    for (int u = 0; u < 2; u++) {
      int c0 = u * 4 + half * 2;
      float4 a0 = *(const float4*)&lA[arow * 32 + (c0 ^ rs) * 4];
      float4 a1 = *(const float4*)&lA[arow * 32 + ((c0 + 1) ^ rs) * 4];
      short8 ah, al8;
      tsplit8(a0, a1, ah, al8);
#pragma unroll
      for (int j = 0; j < NSUBT; j++) {
        short8 cbj = *(const short8*)&lB[(u * NSUBS + ntile * NSUBT + j) * 512 +
                                         lane * 8];
        acc[j] = __builtin_amdgcn_mfma_f32_32x32x16_bf16(ah, cbj, acc[j], 0, 0, 0);
        acc[j] =
            __builtin_amdgcn_mfma_f32_32x32x16_bf16(al8, cbj, acc[j], 0, 0, 0);
      }
    }
    // WAR guard: my LDS reads retired, then all waves synced, before next
    // iter re-stages this buffer.
    asm volatile("s_waitcnt lgkmcnt(0)" ::: "memory");
    __builtin_amdgcn_s_barrier();
    buf ^= 1;
  }

  // C/D layout (m74/m101): col=lane&31, row=(r&3)+8*(r>>2)+4*half
  const int mrow0 = block_row0 + local_mt * 32;
#pragma unroll
  for (int h = 0; h < HPW; h++) {
    int c0 = ntile * NSUBT * 32 + 2 * h * 32 + l31;
    float wa0 = alv[c0], wa1 = alv[c0 + 32];
    float wr0 = arv[c0], wr1 = arv[c0 + 32];
#pragma unroll
    for (int r = 0; r < 16; r++) {
      int roff = (r & 3) + 8 * (r >> 2) + 4 * half;
      int row = mrow0 + roff;
      float v0 = acc[2 * h][r], v1 = acc[2 * h + 1][r];
      if (row < M) {
        Cb[(size_t)row * N + c0] = (unsigned short)bf16rne(v0);
        Cb[(size_t)row * N + c0 + 32] = (unsigned short)bf16rne(v1);
      }
      float elv = v0 * wa0 + v1 * wa1;
      float erv = v0 * wr0 + v1 * wr1;
#pragma unroll
      for (int off = 1; off < 32; off <<= 1) {
        elv += __shfl_xor(elv, off);
        erv += __shfl_xor(erv, off);
      }
      if (l31 == 0 && row < M) {
        int hg = ntile * HPW + h;
        elt[(size_t)row * NHEADS + hg] =
            make_float2(__expf(elv), __expf(NEG_SLOPE * elv));
        ert[(size_t)row * NHEADS + hg] =
            make_float2(__expf(erv), __expf(NEG_SLOPE * erv));
      }
    }
  }
}

// ---------------- CSR build ----------------
__global__ void hist_kernel(const int* __restrict__ dst,
                            int* __restrict__ counts) {
  int e = blockIdx.x * blockDim.x + threadIdx.x;
  if (e < N_EDGES) atomicAdd(&counts[dst[e]], 1);
}

#define NSCAN 196  // ceil(50000/256)
__global__ __launch_bounds__(256) void scan_part(const int* __restrict__ counts,
                                                 int* __restrict__ offsets,
                                                 int* __restrict__ bsums) {
  __shared__ int sh[256];
  int t = threadIdx.x;
  int i = blockIdx.x * 256 + t;
  int v = (i < N_NODES) ? counts[i] : 0;
  sh[t] = v;
  __syncthreads();
  for (int o = 1; o < 256; o <<= 1) {
    int x = (t >= o) ? sh[t - o] : 0;
    __syncthreads();
    sh[t] += x;
    __syncthreads();
  }
  if (i < N_NODES) offsets[i] = sh[t] - v;
  if (t == 255) bsums[blockIdx.x] = sh[255];
}
__global__ __launch_bounds__(256) void scan_top(int* __restrict__ bsums) {
  __shared__ int sh[256];
  int t = threadIdx.x;
  int v = (t < NSCAN) ? bsums[t] : 0;
  sh[t] = v;
  __syncthreads();
  for (int o = 1; o < 256; o <<= 1) {
    int x = (t >= o) ? sh[t - o] : 0;
    __syncthreads();
    sh[t] += x;
    __syncthreads();
  }
  if (t < NSCAN) bsums[t] = sh[t] - v;
}
__global__ __launch_bounds__(256) void scan_add(int* __restrict__ offsets,
                                                const int* __restrict__ bsums) {
  int i = blockIdx.x * 256 + threadIdx.x;
  if (i < N_NODES) offsets[i] += bsums[blockIdx.x];
  if (i == 0) offsets[N_NODES] = N_EDGES;
}

__global__ void scatter_kernel(const int* __restrict__ src,
                               const int* __restrict__ dst,
                               const int* __restrict__ offsets,
                               int* __restrict__ fill,
                               int* __restrict__ csr_src) {
  int e = blockIdx.x * blockDim.x + threadIdx.x;
  if (e < N_EDGES) {
    int d = dst[e];
    int pos = offsets[d] + atomicAdd(&fill[d], 1);
    csr_src[pos] = src[e];
  }
}

// ---------------- aggregation layer 1 v4: wave-per-node ----------------
// 64 lanes each own 4 output dims (float4 acc). Per edge: coalesced 512B row
// gather (uint2/lane), coefficient via exp-tables (uniform per 16-lane head
// group -> denominator accumulated redundantly per lane, NO cross-lane
// reduce, no LDS, no barriers). 4x edge unroll for gather ILP.
__global__ __launch_bounds__(256) void agg1_kernel(
    const int* __restrict__ offsets, const int* __restrict__ csr_src,
    const float2* __restrict__ elt, const float2* __restrict__ ert,
    const unsigned short* __restrict__ fb, const float* __restrict__ bias,
    float* __restrict__ h1) {
  int w = threadIdx.x >> 6, lane = threadIdx.x & 63;
  int n = blockIdx.x * 4 + w;
  if (n >= N_NODES) return;
  int h = lane >> 4;  // head for this lane's 4 dims
  int off0 = offsets[n], deg = offsets[n + 1] - off0;
  float2 fv = ert[n * 4 + h];  // {F1, F2}
  float4 acc = {0.f, 0.f, 0.f, 0.f};
  float4 acc2 = {0.f, 0.f, 0.f, 0.f};
  float sden = 0.f, sden2 = 0.f;
  const unsigned short* fbl = fb + lane * 4;
  int i = 0;
  for (; i + 3 < deg; i += 4) {
    int s0 = csr_src[off0 + i];
    int s1 = csr_src[off0 + i + 1];
    int s2 = csr_src[off0 + i + 2];
    int s3 = csr_src[off0 + i + 3];
    uint2 p0 = *(const uint2*)(fbl + (size_t)s0 * 256);
    uint2 p1 = *(const uint2*)(fbl + (size_t)s1 * 256);
    uint2 p2 = *(const uint2*)(fbl + (size_t)s2 * 256);
    uint2 p3 = *(const uint2*)(fbl + (size_t)s3 * 256);
    float2 q0 = elt[s0 * 4 + h];
    float2 q1 = elt[s1 * 4 + h];
    float2 q2 = elt[s2 * 4 + h];
    float2 q3 = elt[s3 * 4 + h];
    float t0 = q0.x * fv.x, u0 = q0.y * fv.y;
    float t1 = q1.x * fv.x, u1 = q1.y * fv.y;
    float t2 = q2.x * fv.x, u2 = q2.y * fv.y;
    float t3 = q3.x * fv.x, u3 = q3.y * fv.y;
    float a0 = t0 > 1.f ? t0 : u0;
    float a1 = t1 > 1.f ? t1 : u1;
    float a2 = t2 > 1.f ? t2 : u2;
    float a3 = t3 > 1.f ? t3 : u3;
    sden += a0 + a2;
    sden2 += a1 + a3;
    acc.x += a0 * __uint_as_float(p0.x << 16);
    acc.y += a0 * __uint_as_float(p0.x & 0xffff0000u);
    acc.z += a0 * __uint_as_float(p0.y << 16);
    acc.w += a0 * __uint_as_float(p0.y & 0xffff0000u);
    acc2.x += a1 * __uint_as_float(p1.x << 16);
    acc2.y += a1 * __uint_as_float(p1.x & 0xffff0000u);
    acc2.z += a1 * __uint_as_float(p1.y << 16);
    acc2.w += a1 * __uint_as_float(p1.y & 0xffff0000u);
    acc.x += a2 * __uint_as_float(p2.x << 16);
    acc.y += a2 * __uint_as_float(p2.x & 0xffff0000u);
    acc.z += a2 * __uint_as_float(p2.y << 16);
    acc.w += a2 * __uint_as_float(p2.y & 0xffff0000u);
    acc2.x += a3 * __uint_as_float(p3.x << 16);
    acc2.y += a3 * __uint_as_float(p3.x & 0xffff0000u);
    acc2.z += a3 * __uint_as_float(p3.y << 16);
    acc2.w += a3 * __uint_as_float(p3.y & 0xffff0000u);
  }
  for (; i < deg; i++) {
    int s0 = csr_src[off0 + i];
    uint2 p0 = *(const uint2*)(fbl + (size_t)s0 * 256);
    float2 q0 = elt[s0 * 4 + h];
    float t0 = q0.x * fv.x, u0 = q0.y * fv.y;
    float a0 = t0 > 1.f ? t0 : u0;
    sden += a0;
    acc.x += a0 * __uint_as_float(p0.x << 16);
    acc.y += a0 * __uint_as_float(p0.x & 0xffff0000u);
    acc.z += a0 * __uint_as_float(p0.y << 16);
    acc.w += a0 * __uint_as_float(p0.y & 0xffff0000u);
  }
  acc.x += acc2.x;
  acc.y += acc2.y;
  acc.z += acc2.z;
  acc.w += acc2.w;
  sden += sden2;
  float invd = sden > 0.f ? 1.0f / sden : 0.f;
  float4 b = ((const float4*)bias)[lane];
  float o[4] = {acc.x * invd + b.x, acc.y * invd + b.y, acc.z * invd + b.z,
                acc.w * invd + b.w};
#pragma unroll
  for (int j = 0; j < 4; j++) o[j] = o[j] > 0.f ? o[j] : __expf(o[j]) - 1.0f;
  float4 ov = {o[0], o[1], o[2], o[3]};
  *(float4*)(h1 + (size_t)n * 256 + lane * 4) = ov;
}

// ---------------- aggregation layer 2 v3 (tables, fused den, 2x unroll) -----
__global__ __launch_bounds__(256) void agg2_kernel(
    const int* __restrict__ offsets, const int* __restrict__ csr_src,
    const float2* __restrict__ elt, const float2* __restrict__ ert,
    const unsigned short* __restrict__ fb2, const float* __restrict__ bias,
    float* __restrict__ out) {
  int w = threadIdx.x >> 6, lane = threadIdx.x & 63;
  int n = blockIdx.x * 4 + w;
  if (n >= N_NODES) return;
  int dg = lane & 15, eslot = lane >> 4;
  int off0 = offsets[n], deg = offsets[n + 1] - off0;
  float2 fv = ert[n];
  float4 acc = {0.f, 0.f, 0.f, 0.f};
  float4 acc2 = {0.f, 0.f, 0.f, 0.f};
  float sden = 0.f;
  int i = eslot;
  for (; i + 4 < deg; i += 8) {
    int s0 = csr_src[off0 + i];
    int s1 = csr_src[off0 + i + 4];
    uint2 p0 = *(const uint2*)(fb2 + (size_t)s0 * 64 + dg * 4);
    uint2 p1 = *(const uint2*)(fb2 + (size_t)s1 * 64 + dg * 4);
    float2 q0 = elt[s0];
    float2 q1 = elt[s1];
    float t10 = q0.x * fv.x, t20 = q0.y * fv.y;
    float t11 = q1.x * fv.x, t21 = q1.y * fv.y;
    float a0 = t10 > 1.f ? t10 : t20;
    float a1 = t11 > 1.f ? t11 : t21;
    sden += a0 + a1;
    acc.x += a0 * __uint_as_float(p0.x << 16);
    acc.y += a0 * __uint_as_float(p0.x & 0xffff0000u);
    acc.z += a0 * __uint_as_float(p0.y << 16);
    acc.w += a0 * __uint_as_float(p0.y & 0xffff0000u);
    acc2.x += a1 * __uint_as_float(p1.x << 16);
    acc2.y += a1 * __uint_as_float(p1.x & 0xffff0000u);
    acc2.z += a1 * __uint_as_float(p1.y << 16);
    acc2.w += a1 * __uint_as_float(p1.y & 0xffff0000u);
  }
  if (i < deg) {
    int s0 = csr_src[off0 + i];
    uint2 p0 = *(const uint2*)(fb2 + (size_t)s0 * 64 + dg * 4);
    float2 q0 = elt[s0];
    float t10 = q0.x * fv.x, t20 = q0.y * fv.y;
    float a0 = t10 > 1.f ? t10 : t20;
    sden += a0;
    acc.x += a0 * __uint_as_float(p0.x << 16);
    acc.y += a0 * __uint_as_float(p0.x & 0xffff0000u);
    acc.z += a0 * __uint_as_float(p0.y << 16);
    acc.w += a0 * __uint_as_float(p0.y & 0xffff0000u);
  }
  acc.x += acc2.x;
  acc.y += acc2.y;
  acc.z += acc2.z;
  acc.w += acc2.w;
#pragma unroll
  for (int off = 16; off < 64; off <<= 1) {
    acc.x += __shfl_xor(acc.x, off);
    acc.y += __shfl_xor(acc.y, off);
    acc.z += __shfl_xor(acc.z, off);
    acc.w += __shfl_xor(acc.w, off);
    sden += __shfl_xor(sden, off);
  }
  if (eslot == 0) {
    float invd = sden > 0.f ? 1.0f / sden : 0.f;
    float4 b = ((const float4*)bias)[dg];
    float4 ov = {acc.x * invd + b.x, acc.y * invd + b.y, acc.z * invd + b.z,
                 acc.w * invd + b.w};
    *(float4*)(out + (size_t)n * 64 + dg * 4) = ov;
  }
}

extern "C" void kernel_launch(void* const* d_in, const int* in_sizes, int n_in,
                              void* d_out, int out_size, void* d_ws,
                              size_t ws_size, hipStream_t stream) {
  const float* features = (const float*)d_in[0];
  const float* W1 = (const float*)d_in[1];
  const float* al1 = (const float*)d_in[2];
  const float* ar1 = (const float*)d_in[3];
  const float* b1 = (const float*)d_in[4];
  const float* W2 = (const float*)d_in[5];
  const float* al2 = (const float*)d_in[6];
  const float* ar2 = (const float*)d_in[7];
  const float* b2 = (const float*)d_in[8];
  const int* src = (const int*)d_in[9];
  const int* dst = (const int*)d_in[10];
  float* out = (float*)d_out;

  // Workspace (~84 MB):
  //  h1 fp32 [N,256] (agg1 out -> gemm2 A)
  //  fb bf16 [N,256] (gemm1 out) -> dead after agg1 -> fb2 bf16 [N,64] reuses
  //  exp-tables: elt/ert float2 per (node,head)
  float* h1 = (float*)d_ws;                                            // 51.2
  unsigned short* fb = (unsigned short*)(h1 + (size_t)N_NODES * 256);  // 25.6
  unsigned short* fb2 = fb;  // reuse (6.4 MB needed)
  float2* elt1 = (float2*)(fb + (size_t)N_NODES * 256);
  float2* ert1 = elt1 + (size_t)N_NODES * 4;
  float2* elt2 = ert1 + (size_t)N_NODES * 4;
  float2* ert2 = elt2 + N_NODES;
  int* counts = (int*)(ert2 + N_NODES);
  int* offsets = counts + N_NODES;
  int* fill = offsets + N_NODES + 1;
  int* csr_src = fill + N_NODES;
  int* bsums = csr_src + N_EDGES;

  // W packs (hi plane only): b1 in d_out (dead until agg2);
  // b2 in `fill` (dead after scatter).
  short* b1hi = (short*)d_out;   // 512*256 shorts = 262 KB << 12.8 MB
  short* b2hi = (short*)fill;    // 256*64 shorts = 32 KB << 200 KB

  // --- CSR build ---
  hipMemsetAsync(counts, 0, N_NODES * sizeof(int), stream);
  hipMemsetAsync(fill, 0, N_NODES * sizeof(int), stream);
  hist_kernel<<<(N_EDGES + 255) / 256, 256, 0, stream>>>(dst, counts);
  scan_part<<<NSCAN, 256, 0, stream>>>(counts, offsets, bsums);
  scan_top<<<1, 256, 0, stream>>>(bsums);
  scan_add<<<NSCAN, 256, 0, stream>>>(offsets, bsums);
  scatter_kernel<<<(N_EDGES + 255) / 256, 256, 0, stream>>>(src, dst, offsets,
                                                            fill, csr_src);

  // --- weight packing ---
  pack_w<<<512, 256, 0, stream>>>(W1, b1hi, 256);
  pack_w<<<256, 64, 0, stream>>>(W2, b2hi, 64);

  // --- layer 1 (el/er exp-tables fused into gemm epilogue) ---
  gemm_mfma<IN_DIM, 8, 4><<<1563, 256, 0, stream>>>(features, b1hi, fb, al1,
                                                    ar1, elt1, ert1, N_NODES);
  agg1_kernel<<<(N_NODES + 3) / 4, 256, 0, stream>>>(offsets, csr_src, elt1,
                                                     ert1, fb, b1, h1);

  // --- layer 2 ---
  gemm_mfma<256, 2, 1><<<391, 256, 0, stream>>>(h1, b2hi, fb2, al2, ar2, elt2,
                                                ert2, N_NODES);
  agg2_kernel<<<(N_NODES + 3) / 4, 256, 0, stream>>>(offsets, csr_src, elt2,
                                                     ert2, fb2, b2, out);
}